// Round 17
// baseline (4229.563 us; speedup 1.0000x reference)
//
#include <hip/hip_runtime.h>

typedef __attribute__((ext_vector_type(4))) float  f32x4;
typedef __attribute__((ext_vector_type(8))) short  bf16x8;
typedef __attribute__((ext_vector_type(4))) short  bf16x4;

#define NTHR 512
#define BT   64
#define L2E  1.4426950408889634f

// ---------------- LDS byte map (total 75728 <= 81920 -> 2 blocks/CU) ----------------
#define PLANE(L)   ((L)*8192)             // [64 elems][64 units] bf16, XOR-swizzled
#define QB0        24576                  // 16KB stage buffer 0 (one ks-quarter)
#define QB1        40960                  // 16KB stage buffer 1
#define XFB_OFF    57344                  // [64][4] f32 feedback x (1024B)
#define Y1_OFF     58368                  // [64][36] bf16, 72B row (4608B)
#define Y2_OFF     62976                  // [64][18] bf16, 36B row (2304B)
#define BGL_OFF    65280                  // [3][256] f32 bias sums, log2e-scaled (3072B)
#define W0L_OFF    68352                  // [256][4] f32, 16B stride, log2e-scaled (4096B)
#define B3L_OFF    72448                  // [4] f32
#define W3L_OFF    72464                  // [3][16] f32 (192B)
#define OUT_OFF    72656                  // [64][12] f32 out ring, 4 steps (3072B)
#define LDS_TOTAL  75728

// frag-ordered SINGLE-bf16 gate weights (log2e-prescaled): 5 mats * 32KB
__device__ __align__(16) unsigned char g_wsbuf[163840];

__device__ __forceinline__ unsigned short f2bf(float v) {
    unsigned int x = __float_as_uint(v);
    unsigned int r = x + 0x7fffu + ((x >> 16) & 1u);
    return (unsigned short)(r >> 16);
}
__device__ __forceinline__ float bf2f_lo(unsigned int d) { return __uint_as_float(d << 16); }
__device__ __forceinline__ float bf2f_hi(unsigned int d) { return __uint_as_float(d & 0xffff0000u); }

__device__ __forceinline__ float fsig2(float y) {   // sigmoid(x), y = x*log2e
    return __builtin_amdgcn_rcpf(1.0f + __builtin_amdgcn_exp2f(-y));
}
__device__ __forceinline__ float ftanh2(float y) {  // tanh(x), y = 2x*log2e
    return 1.0f - 2.0f * __builtin_amdgcn_rcpf(1.0f + __builtin_amdgcn_exp2f(y));
}
__device__ __forceinline__ float ftanhc(float c) {  // tanh(c)
    return 1.0f - 2.0f * __builtin_amdgcn_rcpf(1.0f + __builtin_amdgcn_exp2f(c * (2.0f * L2E)));
}

// ---------------- prologue: frag-order single-bf16 + log2e prescale (unchanged) ----------------
__global__ void prep_weights(const float* __restrict__ whh0, const float* __restrict__ wih1,
                             const float* __restrict__ whh1, const float* __restrict__ wih2,
                             const float* __restrict__ whh2)
{
    int gi = blockIdx.x * 256 + threadIdx.x;
    if (gi < 10240) {
        int m = gi / 2048;
        int rem = gi & 2047;
        int b = rem >> 6, l = rem & 63;
        int ks = b & 1, g = (b >> 1) & 3, ug = b >> 3;
        int row = g * 64 + ug * 16 + (l & 15);
        int kb  = ks * 32 + (l >> 4) * 8;
        float fac = (g == 2) ? (2.0f * L2E) : L2E;
        const float* src = (m == 0) ? whh0 : (m == 1) ? wih1 : (m == 2) ? whh1
                         : (m == 3) ? wih2 : whh2;
        unsigned short o[8];
        #pragma unroll
        for (int i = 0; i < 8; ++i)
            o[i] = f2bf(src[row * 64 + kb + i] * fac);
        unsigned char* dst = g_wsbuf + m * 32768 + b * 1024 + l * 16;
        #pragma unroll
        for (int i = 0; i < 8; ++i) ((unsigned short*)dst)[i] = o[i];
    }
}

#define MFMA_(A,B,C) __builtin_amdgcn_mfma_f32_16x16x32_bf16(A, B, C, 0, 0, 0)

// phase barrier (R8-proven)
#define BARX do { \
    asm volatile("s_waitcnt lgkmcnt(0)" ::: "memory"); \
    __builtin_amdgcn_s_barrier(); \
    __builtin_amdgcn_sched_barrier(0); \
    } while (0)

// 512-thread staging of one 16KB ks-quarter via 2 regs.
// slot[p]*1024 holds matrix block b = p*2+ks; R0 -> p = tid>>6, R1 -> p = 8+(tid>>6)
#define LOADQ2(m, ks, R0, R1) do { \
    R0 = *(const bf16x8*)(g_wsbuf + (m) * 32768 + \
        (((tid >> 6) * 2 + (ks))) * 1024 + (tid & 63) * 16); \
    R1 = *(const bf16x8*)(g_wsbuf + (m) * 32768 + \
        (((tid >> 6) * 2 + (ks)) + 16) * 1024 + (tid & 63) * 16); \
    } while (0)
#define COMMITQ2(R0, R1, BUF) do { \
    *(bf16x8*)(lds + (BUF) + (tid >> 6) * 1024 + (tid & 63) * 16) = R0; \
    *(bf16x8*)(lds + (BUF) + ((tid >> 6) + 8) * 1024 + (tid & 63) * 16) = R1; \
    } while (0)

#define ACC_INIT(L) do { \
    _Pragma("unroll") for (int g_ = 0; g_ < 4; ++g_) { \
        float b_ = *(const float*)(lds + BGL_OFF + ((L) * 256 + g_ * 64 + u) * 4); \
        f32x4 t_ = {b_, b_, b_, b_}; \
        acc[g_][0] = t_; acc[g_][1] = t_; \
    } } while (0)

// gate pass: acc += bf16(h) x staged quarter (6 ds_read_b128, 16 MFMA)
#define GATEP(APL, ks, BUF) do { \
    bf16x8 b_[4]; \
    _Pragma("unroll") for (int g_ = 0; g_ < 4; ++g_) \
        b_[g_] = *(const bf16x8*)(lds + (BUF) + (ug * 4 + g_) * 1024 + lane * 16); \
    _Pragma("unroll") for (int mt_ = 0; mt_ < 2; ++mt_) { \
        int ab_ = (((mbase + mt_ * 16 + l15) * 128 + (ks) * 64 + l4 * 16)) ^ rswz; \
        bf16x8 ah_ = *(const bf16x8*)(lds + PLANE(APL) + ab_); \
        _Pragma("unroll") for (int g_ = 0; g_ < 4; ++g_) \
            acc[g_][mt_] = MFMA_(ah_, b_[g_], acc[g_][mt_]); \
    } } while (0)

#define CELLW(L, CARR) do { \
    _Pragma("unroll") for (int mt_ = 0; mt_ < 2; ++mt_) \
    _Pragma("unroll") for (int r_ = 0; r_ < 4; ++r_) { \
        float gi_ = fsig2(acc[0][mt_][r_]); \
        float gf_ = fsig2(acc[1][mt_][r_]); \
        float gg_ = ftanh2(acc[2][mt_][r_]); \
        float go_ = fsig2(acc[3][mt_][r_]); \
        float cn_ = gf_ * CARR[mt_ * 4 + r_] + gi_ * gg_; \
        CARR[mt_ * 4 + r_] = cn_; \
        float hn_ = go_ * ftanhc(cn_); \
        int e_ = mbase + mt_ * 16 + l4 * 4 + r_; \
        int wb_ = ((e_ * 128 + u * 2)) ^ ((e_ & 7) << 4); \
        *(unsigned short*)(lds + PLANE(L) + wb_) = f2bf(hn_); \
    } } while (0)

#define XPART do { \
    _Pragma("unroll") for (int mt_ = 0; mt_ < 2; ++mt_) \
    _Pragma("unroll") for (int r_ = 0; r_ < 4; ++r_) { \
        int e_ = mbase + mt_ * 16 + l4 * 4 + r_; \
        f32x4 xv_ = *(const f32x4*)(lds + XFB_OFF + e_ * 16); \
        _Pragma("unroll") for (int g_ = 0; g_ < 4; ++g_) { \
            f32x4 w0_ = *(const f32x4*)(lds + W0L_OFF + (g_ * 64 + u) * 16); \
            acc[g_][mt_][r_] += xv_.x * w0_.x + xv_.y * w0_.y + xv_.z * w0_.z; \
        } } } while (0)

// y1 via MFMA, w1 frags resident in registers (2 MFMA)
#define MLP1 do { \
    int Mt_ = wv >> 1; \
    f32x4 a1_ = {b1r, b1r, b1r, b1r}; \
    { int ab_ = (((Mt_ * 16 + l15) * 128 + 0 * 64 + l4 * 16)) ^ rswz; \
      bf16x8 ah_ = *(const bf16x8*)(lds + PLANE(2) + ab_); \
      a1_ = MFMA_(ah_, w1f0, a1_); } \
    { int ab_ = (((Mt_ * 16 + l15) * 128 + 1 * 64 + l4 * 16)) ^ rswz; \
      bf16x8 ah_ = *(const bf16x8*)(lds + PLANE(2) + ab_); \
      a1_ = MFMA_(ah_, w1f1, a1_); } \
    _Pragma("unroll") for (int r_ = 0; r_ < 4; ++r_) { \
        float y_ = a1_[r_]; y_ = (y_ >= 0.f) ? y_ : 0.01f * y_; \
        int e_ = Mt_ * 16 + l4 * 4 + r_; \
        *(unsigned short*)(lds + Y1_OFF + e_ * 72 + hf * 32 + l15 * 2) = f2bf(y_); \
    } } while (0)

// y2 via MFMA on waves 0..3 (1 MFMA)
#define MLP2M do { \
    if (wv < 4) { \
        bf16x4 alo_ = *(const bf16x4*)(lds + Y1_OFF + (wv * 16 + l15) * 72 + l4 * 16); \
        bf16x4 ahi_ = *(const bf16x4*)(lds + Y1_OFF + (wv * 16 + l15) * 72 + l4 * 16 + 8); \
        bf16x8 af_ = {alo_[0], alo_[1], alo_[2], alo_[3], \
                      ahi_[0], ahi_[1], ahi_[2], ahi_[3]}; \
        f32x4 a2_ = {b2r, b2r, b2r, b2r}; \
        a2_ = MFMA_(af_, w2f, a2_); \
        _Pragma("unroll") for (int r_ = 0; r_ < 4; ++r_) { \
            float y_ = a2_[r_]; y_ = (y_ >= 0.f) ? y_ : 0.01f * y_; \
            int e_ = wv * 16 + l4 * 4 + r_; \
            *(unsigned short*)(lds + Y2_OFF + e_ * 36 + l15 * 2) = f2bf(y_); \
        } } } while (0)

#define MLP3_OUT do { \
    if (tid < 192) { \
        int e3_ = tid & 63, r3_ = tid >> 6; \
        float a3_ = *(const float*)(lds + B3L_OFF + r3_ * 4); \
        _Pragma("unroll") for (int kd_ = 0; kd_ < 8; ++kd_) { \
            unsigned int d_ = *(const unsigned int*)(lds + Y2_OFF + e3_ * 36 + kd_ * 4); \
            a3_ = fmaf(bf2f_lo(d_), *(const float*)(lds + W3L_OFF + (r3_ * 16 + kd_ * 2) * 4),     a3_); \
            a3_ = fmaf(bf2f_hi(d_), *(const float*)(lds + W3L_OFF + (r3_ * 16 + kd_ * 2 + 1) * 4), a3_); \
        } \
        float y_ = (a3_ >= 0.f) ? a3_ : 0.01f * a3_; \
        *(float*)(lds + XFB_OFF + e3_ * 16 + r3_ * 4) = y_; \
        *(float*)(lds + OUT_OFF + e3_ * 48 + (t & 3) * 12 + r3_ * 4) = y_; \
    } } while (0)

// ---------------- main persistent kernel: 512 thr (8 waves), 2 blocks/CU ----------------
extern "C" __global__ void __launch_bounds__(NTHR)
__attribute__((amdgpu_waves_per_eu(4)))
lstm_mfma(const float* __restrict__ noise,
          const float* __restrict__ wih0, const float* __restrict__ whh0,
          const float* __restrict__ bih0, const float* __restrict__ bhh0,
          const float* __restrict__ wih1, const float* __restrict__ whh1,
          const float* __restrict__ bih1, const float* __restrict__ bhh1,
          const float* __restrict__ wih2, const float* __restrict__ whh2,
          const float* __restrict__ bih2, const float* __restrict__ bhh2,
          const float* __restrict__ w1g, const float* __restrict__ b1g,
          const float* __restrict__ w2g, const float* __restrict__ b2g,
          const float* __restrict__ w3g, const float* __restrict__ b3g,
          const int* __restrict__ lenp, float* __restrict__ out)
{
    extern __shared__ unsigned char lds[];
    const int tid  = threadIdx.x;
    const int lane = tid & 63;
    const int wv   = tid >> 6;       // wave 0..7
    const int ug   = wv & 3;         // unit group (16 units)
    const int mh   = wv >> 2;        // M half 0..1
    const int l15  = lane & 15;
    const int l4   = lane >> 4;      // k-group
    const int u    = ug * 16 + l15;  // unit 0..63
    const int mbase = mh * 32;
    const int rswz  = (lane & 7) << 4;
    const int hf    = wv & 1;        // MLP1 col-half
    const int T = *lenp;
    const long eg0  = (long)blockIdx.x * BT;
    const long outs = 3L * T;

    // per-thread recurrent c state
    float c0[8], c1[8], c2[8];
    #pragma unroll
    for (int i = 0; i < 8; ++i) { c0[i] = 0.f; c1[i] = 0.f; c2[i] = 0.f; }

    // resident MLP weight fragments / biases
    bf16x8 w1f0, w1f1, w2f;
    {
        const float* p0 = w1g + (hf * 16 + l15) * 64 + l4 * 8;
        w1f0 = (bf16x8){(short)f2bf(p0[0]), (short)f2bf(p0[1]), (short)f2bf(p0[2]),
                        (short)f2bf(p0[3]), (short)f2bf(p0[4]), (short)f2bf(p0[5]),
                        (short)f2bf(p0[6]), (short)f2bf(p0[7])};
        const float* p1 = p0 + 32;
        w1f1 = (bf16x8){(short)f2bf(p1[0]), (short)f2bf(p1[1]), (short)f2bf(p1[2]),
                        (short)f2bf(p1[3]), (short)f2bf(p1[4]), (short)f2bf(p1[5]),
                        (short)f2bf(p1[6]), (short)f2bf(p1[7])};
        const float* p2 = w2g + l15 * 32 + l4 * 8;
        w2f  = (bf16x8){(short)f2bf(p2[0]), (short)f2bf(p2[1]), (short)f2bf(p2[2]),
                        (short)f2bf(p2[3]), (short)f2bf(p2[4]), (short)f2bf(p2[5]),
                        (short)f2bf(p2[6]), (short)f2bf(p2[7])};
    }
    const float b1r = b1g[hf * 16 + l15];
    const float b2r = b2g[l15];

    // 2-register-pair staging ping-pong + prologue temp
    bf16x8 RB0, RB1, RC0, RC1, RT0, RT1;
    LOADQ2(1, 0, RT0, RT1);          // q2 (wih1 ks0)
    LOADQ2(1, 1, RB0, RB1);          // q3
    LOADQ2(2, 0, RC0, RC1);          // q4

    // ---- LDS init ----
    for (int i = tid; i < 24576 / 4; i += NTHR) ((unsigned int*)lds)[i] = 0u;  // h planes = 0
    if (tid < BT) {
        const float* np = noise + (eg0 + tid) * 3;
        f32x4 xv = {np[0], np[1], np[2], 0.f};
        *(f32x4*)(lds + XFB_OFF + tid * 16) = xv;
    }
    for (int i = tid; i < 768; i += NTHR) {            // bias sums, log2e-scaled
        int l = i >> 8, r = i & 255, g = r >> 6;
        float fac = (g == 2) ? (2.0f * L2E) : L2E;
        const float* bi = (l == 0) ? bih0 : ((l == 1) ? bih1 : bih2);
        const float* bh = (l == 0) ? bhh0 : ((l == 1) ? bhh1 : bhh2);
        *(float*)(lds + BGL_OFF + i * 4) = (bi[r] + bh[r]) * fac;
    }
    if (tid < 256) {                                   // wih0, log2e-scaled
        int g = tid >> 6;
        float fac = (g == 2) ? (2.0f * L2E) : L2E;
        f32x4 wv0 = {wih0[tid * 3] * fac, wih0[tid * 3 + 1] * fac,
                     wih0[tid * 3 + 2] * fac, 0.f};
        *(f32x4*)(lds + W0L_OFF + tid * 16) = wv0;
    }
    if (tid < 3)  *(float*)(lds + B3L_OFF + tid * 4) = b3g[tid];
    if (tid < 48) *(float*)(lds + W3L_OFF + tid * 4) = w3g[tid];

    __syncthreads();                 // init visible
    COMMITQ2(RT0, RT1, QB0);         // q2 -> b0

    f32x4 acc[4][2];
    ACC_INIT(0);                     // t=0: gates0 = bias (whh0 . 0 == 0)
    __syncthreads();                 // b0 ready

    // quarters q0..q9 = (m,ks): whh0{0,1} wih1{2,3} whh1{4,5} wih2{6,7} whh2{8,9}
    #pragma unroll 1
    for (int t = 0; t < T; ++t) {
        // P1: x-part + CELL0 (acc holds bias + whh0*h0_old from P12/P13 of t-1)
        XPART;
        CELLW(0, c0);                               // h0 -> plane0
        BARX;
        // P2: GATE q2 (wih1 ks0, A=plane0 new)
        COMMITQ2(RB0, RB1, QB1); LOADQ2(2, 1, RB0, RB1);  // commit q3, load q5
        ACC_INIT(1);
        GATEP(0, 0, QB0);
        BARX;
        // P3: GATE q3 (wih1 ks1)
        COMMITQ2(RC0, RC1, QB0); LOADQ2(3, 0, RC0, RC1);  // commit q4, load q6
        GATEP(0, 1, QB1);
        BARX;
        // P4: GATE q4 (whh1 ks0, A=plane1 old)
        COMMITQ2(RB0, RB1, QB1); LOADQ2(3, 1, RB0, RB1);  // commit q5, load q7
        GATEP(1, 0, QB0);
        BARX;
        // P5: GATE q5 (whh1 ks1)
        COMMITQ2(RC0, RC1, QB0); LOADQ2(4, 0, RC0, RC1);  // commit q6, load q8
        GATEP(1, 1, QB1);
        BARX;
        // P6: CELL1
        CELLW(1, c1);                               // h1 -> plane1
        BARX;
        // P7: GATE q6 (wih2 ks0, A=plane1 new)
        COMMITQ2(RB0, RB1, QB1); LOADQ2(4, 1, RB0, RB1);  // commit q7, load q9
        ACC_INIT(2);
        GATEP(1, 0, QB0);
        BARX;
        // P8: GATE q7 (wih2 ks1)
        COMMITQ2(RC0, RC1, QB0); LOADQ2(0, 0, RC0, RC1);  // commit q8, load q0'
        GATEP(1, 1, QB1);
        BARX;
        // P9: GATE q8 (whh2 ks0, A=plane2 old)
        COMMITQ2(RB0, RB1, QB1); LOADQ2(0, 1, RB0, RB1);  // commit q9, load q1'
        GATEP(2, 0, QB0);
        BARX;
        // P10: GATE q9 (whh2 ks1)
        COMMITQ2(RC0, RC1, QB0); LOADQ2(1, 0, RC0, RC1);  // commit q0', load q2'
        GATEP(2, 1, QB1);
        BARX;
        // P11: CELL2
        CELLW(2, c2);                               // h2 -> plane2
        BARX;
        // P12: MLP1 + GATE q0' (whh0 ks0 for t+1, A=plane0=h0 of t)
        COMMITQ2(RB0, RB1, QB1); LOADQ2(1, 1, RB0, RB1);  // commit q1', load q3'
        MLP1;
        ACC_INIT(0);
        GATEP(0, 0, QB0);
        BARX;
        // P13: MLP2 (MFMA) + GATE q1' (whh0 ks1)
        COMMITQ2(RC0, RC1, QB0); LOADQ2(2, 0, RC0, RC1);  // commit q2', load q4'
        MLP2M;
        GATEP(0, 1, QB1);
        BARX;
        // P14: MLP3 + out ring (+ flush every 4 steps)
        MLP3_OUT;
        if ((t & 3) == 3) {
            BARX;
            long tb = t - 3;
            #pragma unroll
            for (int it = 0; it < 2; ++it) {
                int i = it * NTHR + tid;
                if (i < 768) {
                    int e = i / 12, j = i - e * 12;
                    out[(eg0 + e) * outs + tb * 3 + j] =
                        *(const float*)(lds + OUT_OFF + e * 48 + j * 4);
                }
            }
        }
        BARX;                                       // step boundary (XFB visible)
    }

    // tail flush (T not multiple of 4)
    int nst = T & 3;
    if (nst) {
        int nfl = BT * nst * 3;
        for (int i = tid; i < nfl; i += NTHR) {
            int e = i / (nst * 3), j = i - e * (nst * 3);
            out[(eg0 + e) * outs + (long)(T - nst) * 3 + j] =
                *(const float*)(lds + OUT_OFF + e * 48 + j * 4);
        }
    }
}

extern "C" void kernel_launch(void* const* d_in, const int* in_sizes, int n_in,
                              void* d_out, int out_size, void* d_ws, size_t ws_size,
                              hipStream_t stream)
{
    const float* noise = (const float*)d_in[0];
    const float* wih0  = (const float*)d_in[1];
    const float* whh0  = (const float*)d_in[2];
    const float* bih0  = (const float*)d_in[3];
    const float* bhh0  = (const float*)d_in[4];
    const float* wih1  = (const float*)d_in[5];
    const float* whh1  = (const float*)d_in[6];
    const float* bih1  = (const float*)d_in[7];
    const float* bhh1  = (const float*)d_in[8];
    const float* wih2  = (const float*)d_in[9];
    const float* whh2  = (const float*)d_in[10];
    const float* bih2  = (const float*)d_in[11];
    const float* bhh2  = (const float*)d_in[12];
    const float* w1g   = (const float*)d_in[13];
    const float* b1g   = (const float*)d_in[14];
    const float* w2g   = (const float*)d_in[15];
    const float* b2g   = (const float*)d_in[16];
    const float* w3g   = (const float*)d_in[17];
    const float* b3g   = (const float*)d_in[18];
    const int*   lenp  = (const int*)d_in[19];
    float* out = (float*)d_out;

    int B = in_sizes[0] / 3;              // 32768
    int grid = B / BT;                    // 512 blocks = 2 per CU

    prep_weights<<<40, 256, 0, stream>>>(whh0, wih1, whh1, wih2, whh2);

    hipFuncSetAttribute((const void*)lstm_mfma,
                        hipFuncAttributeMaxDynamicSharedMemorySize, LDS_TOTAL);
    lstm_mfma<<<grid, NTHR, LDS_TOTAL, stream>>>(
        noise, wih0, whh0, bih0, bhh0, wih1, whh1, bih1, bhh1,
        wih2, whh2, bih2, bhh2, w1g, b1g, w2g, b2g, w3g, b3g, lenp, out);
}

// Round 18
// 3607.888 us; speedup vs baseline: 1.1723x; 1.1723x over previous
//
#include <hip/hip_runtime.h>

typedef __attribute__((ext_vector_type(4))) float  f32x4;
typedef __attribute__((ext_vector_type(8))) short  bf16x8;
typedef __attribute__((ext_vector_type(4))) short  bf16x4;

#define NTHR 1024
#define BT   128
#define L2E  1.4426950408889634f

// ---------------- LDS byte map (total 162512 <= 163840) ----------------
#define PLANE(L)   ((L)*16384)            // [128 elems][64 units] bf16, XOR-swizzled
#define QS(s)      (49152 + (s)*16384)    // 5-slot staging ring (80KB)
#define XFB_OFF    131072                 // [128][4] f32 feedback x (2048B)
#define Y1_OFF     133120                 // [128][36] bf16, 72B row (9216B)
#define Y2_OFF     142336                 // [128][18] bf16, 36B row (4608B)
#define BGL_OFF    146944                 // [3][256] f32 bias sums, log2e-scaled (3072B)
#define W0L_OFF    150016                 // [256][4] f32, 16B stride, log2e-scaled (4096B)
#define B3L_OFF    154112                 // [4] f32
#define W3L_OFF    154128                 // [3][16] f32 (192B)
#define W1L_OFF    154320                 // w1 frag blocks [4][64][16B] (4096B)
#define W2L_OFF    158416                 // [16][32] bf16 (1024B)
#define OUT_OFF    159440                 // [128][6] f32 out ring, 2 steps (3072B)
#define LDS_TOTAL  162512

// frag-ordered SINGLE-bf16 gate weights (log2e-prescaled): 5 mats * 32KB
__device__ __align__(16) unsigned char g_wsbuf[163840];

__device__ __forceinline__ unsigned short f2bf(float v) {
    unsigned int x = __float_as_uint(v);
    unsigned int r = x + 0x7fffu + ((x >> 16) & 1u);
    return (unsigned short)(r >> 16);
}
__device__ __forceinline__ float bf2f_lo(unsigned int d) { return __uint_as_float(d << 16); }
__device__ __forceinline__ float bf2f_hi(unsigned int d) { return __uint_as_float(d & 0xffff0000u); }

__device__ __forceinline__ float fsig2(float y) {   // sigmoid(x), y = x*log2e
    return __builtin_amdgcn_rcpf(1.0f + __builtin_amdgcn_exp2f(-y));
}
__device__ __forceinline__ float ftanh2(float y) {  // tanh(x), y = 2x*log2e
    return 1.0f - 2.0f * __builtin_amdgcn_rcpf(1.0f + __builtin_amdgcn_exp2f(y));
}
__device__ __forceinline__ float ftanhc(float c) {  // tanh(c)
    return 1.0f - 2.0f * __builtin_amdgcn_rcpf(1.0f + __builtin_amdgcn_exp2f(c * (2.0f * L2E)));
}

// ---------------- prologue: frag-order single-bf16 + log2e prescale ----------------
__global__ void prep_weights(const float* __restrict__ whh0, const float* __restrict__ wih1,
                             const float* __restrict__ whh1, const float* __restrict__ wih2,
                             const float* __restrict__ whh2)
{
    int gi = blockIdx.x * 256 + threadIdx.x;
    if (gi < 10240) {
        int m = gi / 2048;
        int rem = gi & 2047;
        int b = rem >> 6, l = rem & 63;
        int ks = b & 1, g = (b >> 1) & 3, ug = b >> 3;
        int row = g * 64 + ug * 16 + (l & 15);
        int kb  = ks * 32 + (l >> 4) * 8;
        float fac = (g == 2) ? (2.0f * L2E) : L2E;
        const float* src = (m == 0) ? whh0 : (m == 1) ? wih1 : (m == 2) ? whh1
                         : (m == 3) ? wih2 : whh2;
        unsigned short o[8];
        #pragma unroll
        for (int i = 0; i < 8; ++i)
            o[i] = f2bf(src[row * 64 + kb + i] * fac);
        unsigned char* dst = g_wsbuf + m * 32768 + b * 1024 + l * 16;
        #pragma unroll
        for (int i = 0; i < 8; ++i) ((unsigned short*)dst)[i] = o[i];
    }
}

#define MFMA_(A,B,C) __builtin_amdgcn_mfma_f32_16x16x32_bf16(A, B, C, 0, 0, 0)

// phase barrier: LDS drain -> barrier -> compiler memory fence (NO sched_barrier —
// isolated A/B vs R15: allow the scheduler to software-pipeline across phases)
#define BARX do { \
    asm volatile("s_waitcnt lgkmcnt(0)" ::: "memory"); \
    __builtin_amdgcn_s_barrier(); \
    asm volatile("" ::: "memory"); \
    } while (0)

// staging: one dwordx4 per thread per 16KB quarter (m, ks)
#define LOADQ(m, ks, R) \
    R = *(const bf16x8*)(g_wsbuf + (m) * 32768 + \
        ((tid >> 6) * 2 + (ks)) * 1024 + (tid & 63) * 16)
#define COMMITQ(R, BUF) \
    *(bf16x8*)(lds + (BUF) + tid * 16) = R

#define ACC_INIT(L) do { \
    _Pragma("unroll") for (int g_ = 0; g_ < 4; ++g_) { \
        float b_ = *(const float*)(lds + BGL_OFF + ((L) * 256 + g_ * 64 + u) * 4); \
        f32x4 t_ = {b_, b_, b_, b_}; \
        acc[g_][0] = t_; acc[g_][1] = t_; \
    } } while (0)

// gate pass: acc += bf16(h_plane) x staged quarter (6 ds_read_b128, 16 MFMA)
#define GATEP(APL, ks, BUF) do { \
    bf16x8 b_[4]; \
    _Pragma("unroll") for (int g_ = 0; g_ < 4; ++g_) \
        b_[g_] = *(const bf16x8*)(lds + (BUF) + (ug * 4 + g_) * 1024 + lane * 16); \
    _Pragma("unroll") for (int mt_ = 0; mt_ < 2; ++mt_) { \
        int ab_ = (((mbase + mt_ * 16 + l15) * 128 + (ks) * 64 + l4 * 16)) ^ rswz; \
        bf16x8 ah_ = *(const bf16x8*)(lds + PLANE(APL) + ab_); \
        _Pragma("unroll") for (int g_ = 0; g_ < 4; ++g_) \
            acc[g_][mt_] = MFMA_(ah_, b_[g_], acc[g_][mt_]); \
    } } while (0)

#define CELLW(L, CARR) do { \
    _Pragma("unroll") for (int mt_ = 0; mt_ < 2; ++mt_) \
    _Pragma("unroll") for (int r_ = 0; r_ < 4; ++r_) { \
        float gi_ = fsig2(acc[0][mt_][r_]); \
        float gf_ = fsig2(acc[1][mt_][r_]); \
        float gg_ = ftanh2(acc[2][mt_][r_]); \
        float go_ = fsig2(acc[3][mt_][r_]); \
        float cn_ = gf_ * CARR[mt_ * 4 + r_] + gi_ * gg_; \
        CARR[mt_ * 4 + r_] = cn_; \
        float hn_ = go_ * ftanhc(cn_); \
        int e_ = mbase + mt_ * 16 + l4 * 4 + r_; \
        int wb_ = ((e_ * 128 + u * 2)) ^ ((e_ & 7) << 4); \
        *(unsigned short*)(lds + PLANE(L) + wb_) = f2bf(hn_); \
    } } while (0)

#define XPART do { \
    _Pragma("unroll") for (int mt_ = 0; mt_ < 2; ++mt_) \
    _Pragma("unroll") for (int r_ = 0; r_ < 4; ++r_) { \
        int e_ = mbase + mt_ * 16 + l4 * 4 + r_; \
        f32x4 xv_ = *(const f32x4*)(lds + XFB_OFF + e_ * 16); \
        _Pragma("unroll") for (int g_ = 0; g_ < 4; ++g_) { \
            f32x4 w0_ = *(const f32x4*)(lds + W0L_OFF + (g_ * 64 + u) * 16); \
            acc[g_][mt_][r_] += xv_.x * w0_.x + xv_.y * w0_.y + xv_.z * w0_.z; \
        } } } while (0)

// y1 via MFMA, w1 frags from resident LDS (2 MFMA)
#define MLP1 do { \
    int Mt_ = wv >> 1; \
    f32x4 a1_ = {b1r, b1r, b1r, b1r}; \
    bf16x8 wh0_ = *(const bf16x8*)(lds + W1L_OFF + (hf * 2 + 0) * 1024 + lane * 16); \
    bf16x8 wh1_ = *(const bf16x8*)(lds + W1L_OFF + (hf * 2 + 1) * 1024 + lane * 16); \
    { int ab_ = (((Mt_ * 16 + l15) * 128 + 0 * 64 + l4 * 16)) ^ rswz; \
      bf16x8 ah_ = *(const bf16x8*)(lds + PLANE(2) + ab_); \
      a1_ = MFMA_(ah_, wh0_, a1_); } \
    { int ab_ = (((Mt_ * 16 + l15) * 128 + 1 * 64 + l4 * 16)) ^ rswz; \
      bf16x8 ah_ = *(const bf16x8*)(lds + PLANE(2) + ab_); \
      a1_ = MFMA_(ah_, wh1_, a1_); } \
    _Pragma("unroll") for (int r_ = 0; r_ < 4; ++r_) { \
        float y_ = a1_[r_]; y_ = (y_ >= 0.f) ? y_ : 0.01f * y_; \
        int e_ = Mt_ * 16 + l4 * 4 + r_; \
        *(unsigned short*)(lds + Y1_OFF + e_ * 72 + hf * 32 + l15 * 2) = f2bf(y_); \
    } } while (0)

// y2 via MFMA on waves 0..7 (1 MFMA)
#define MLP2M do { \
    if (wv < 8) { \
        bf16x4 alo_ = *(const bf16x4*)(lds + Y1_OFF + (wv * 16 + l15) * 72 + l4 * 16); \
        bf16x4 ahi_ = *(const bf16x4*)(lds + Y1_OFF + (wv * 16 + l15) * 72 + l4 * 16 + 8); \
        bf16x8 af_ = {alo_[0], alo_[1], alo_[2], alo_[3], \
                      ahi_[0], ahi_[1], ahi_[2], ahi_[3]}; \
        bf16x8 w2f_ = *(const bf16x8*)(lds + W2L_OFF + (l15 * 32 + l4 * 8) * 2); \
        f32x4 a2_ = {b2r, b2r, b2r, b2r}; \
        a2_ = MFMA_(af_, w2f_, a2_); \
        _Pragma("unroll") for (int r_ = 0; r_ < 4; ++r_) { \
            float y_ = a2_[r_]; y_ = (y_ >= 0.f) ? y_ : 0.01f * y_; \
            int e_ = wv * 16 + l4 * 4 + r_; \
            *(unsigned short*)(lds + Y2_OFF + e_ * 36 + l15 * 2) = f2bf(y_); \
        } } } while (0)

#define MLP3_OUT(tc) do { \
    if (tid < 384) { \
        int e3_ = tid & 127, r3_ = tid >> 7; \
        float a3_ = *(const float*)(lds + B3L_OFF + r3_ * 4); \
        _Pragma("unroll") for (int kd_ = 0; kd_ < 8; ++kd_) { \
            unsigned int d_ = *(const unsigned int*)(lds + Y2_OFF + e3_ * 36 + kd_ * 4); \
            a3_ = fmaf(bf2f_lo(d_), *(const float*)(lds + W3L_OFF + (r3_ * 16 + kd_ * 2) * 4),     a3_); \
            a3_ = fmaf(bf2f_hi(d_), *(const float*)(lds + W3L_OFF + (r3_ * 16 + kd_ * 2 + 1) * 4), a3_); \
        } \
        float y_ = (a3_ >= 0.f) ? a3_ : 0.01f * a3_; \
        *(float*)(lds + XFB_OFF + e3_ * 16 + r3_ * 4) = y_; \
        *(float*)(lds + OUT_OFF + e3_ * 24 + ((tc) & 1) * 12 + r3_ * 4) = y_; \
    } } while (0)

// ---------------- main persistent kernel ----------------
// quarters: I/J = whh0 (0,0/1); C/D = wih1 (1,0/1); A/B = whh1 (2,0/1);
//           G/H = wih2 (3,0/1); E/F = whh2 (4,0/1)
extern "C" __global__ void __launch_bounds__(NTHR)
__attribute__((amdgpu_waves_per_eu(4, 4)))
lstm_mfma(const float* __restrict__ noise,
          const float* __restrict__ wih0, const float* __restrict__ whh0,
          const float* __restrict__ bih0, const float* __restrict__ bhh0,
          const float* __restrict__ wih1, const float* __restrict__ whh1,
          const float* __restrict__ bih1, const float* __restrict__ bhh1,
          const float* __restrict__ wih2, const float* __restrict__ whh2,
          const float* __restrict__ bih2, const float* __restrict__ bhh2,
          const float* __restrict__ w1g, const float* __restrict__ b1g,
          const float* __restrict__ w2g, const float* __restrict__ b2g,
          const float* __restrict__ w3g, const float* __restrict__ b3g,
          const int* __restrict__ lenp, float* __restrict__ out)
{
    extern __shared__ unsigned char lds[];
    const int tid  = threadIdx.x;
    const int lane = tid & 63;
    const int wv   = tid >> 6;       // wave 0..15
    const int ug   = wv & 3;         // unit group (16 units)
    const int mh   = wv >> 2;        // M quarter 0..3
    const int l15  = lane & 15;
    const int l4   = lane >> 4;      // k-group
    const int u    = ug * 16 + l15;  // unit 0..63
    const int mbase = mh * 32;
    const int rswz  = (lane & 7) << 4;
    const int hf    = wv & 1;        // MLP1 col-half
    const int T = *lenp;
    const long eg0  = (long)blockIdx.x * BT;
    const long outs = 3L * T;

    // per-thread recurrent c state
    float c0[8], c1[8], c2[8];
    #pragma unroll
    for (int i = 0; i < 8; ++i) { c0[i] = 0.f; c1[i] = 0.f; c2[i] = 0.f; }

    const float b1r = b1g[hf * 16 + l15];
    const float b2r = b2g[l15];

    // staging regs
    bf16x8 Ra, Rb;

    // prologue loads: A=(2,0), B=(2,1)
    LOADQ(2, 0, Ra);
    LOADQ(2, 1, Rb);

    // ---- LDS init ----
    for (int i = tid; i < 49152 / 4; i += NTHR) ((unsigned int*)lds)[i] = 0u;  // h planes = 0
    if (tid < BT) {
        const float* np = noise + (eg0 + tid) * 3;
        f32x4 xv = {np[0], np[1], np[2], 0.f};
        *(f32x4*)(lds + XFB_OFF + tid * 16) = xv;
    }
    if (tid < 768) {                                   // bias sums, log2e-scaled
        int l = tid >> 8, r = tid & 255, g = r >> 6;
        float fac = (g == 2) ? (2.0f * L2E) : L2E;
        const float* bi = (l == 0) ? bih0 : ((l == 1) ? bih1 : bih2);
        const float* bh = (l == 0) ? bhh0 : ((l == 1) ? bhh1 : bhh2);
        *(float*)(lds + BGL_OFF + tid * 4) = (bi[r] + bh[r]) * fac;
    }
    if (tid < 256) {                                   // wih0, log2e-scaled
        int g = tid >> 6;
        float fac = (g == 2) ? (2.0f * L2E) : L2E;
        f32x4 wv0 = {wih0[tid * 3] * fac, wih0[tid * 3 + 1] * fac,
                     wih0[tid * 3 + 2] * fac, 0.f};
        *(f32x4*)(lds + W0L_OFF + tid * 16) = wv0;
    }
    if (tid < 256) {                                   // w1 frag blocks
        int b = tid >> 6, l = tid & 63;
        int hh = b >> 1, ks = b & 1;
        int row = hh * 16 + (l & 15);
        int kb  = ks * 32 + (l >> 4) * 8;
        unsigned short o[8];
        #pragma unroll
        for (int i = 0; i < 8; ++i) o[i] = f2bf(w1g[row * 64 + kb + i]);
        #pragma unroll
        for (int i = 0; i < 8; ++i)
            *(unsigned short*)(lds + W1L_OFF + b * 1024 + l * 16 + i * 2) = o[i];
    }
    if (tid < 512) *(unsigned short*)(lds + W2L_OFF + tid * 2) = f2bf(w2g[tid]);
    if (tid < 3)   *(float*)(lds + B3L_OFF + tid * 4) = b3g[tid];
    if (tid < 48)  *(float*)(lds + W3L_OFF + tid * 4) = w3g[tid];

    __syncthreads();                 // init visible
    COMMITQ(Ra, QS(0));              // A -> S0
    COMMITQ(Rb, QS(1));              // B -> S1
    LOADQ(1, 0, Ra);                 // C
    COMMITQ(Ra, QS(2));              // C -> S2
    LOADQ(1, 1, Ra);                 // D -> Ra
    LOADQ(4, 0, Rb);                 // E -> Rb

    f32x4 acc[4][2];
    ACC_INIT(0);                     // t=0 layer0 gates = bias (whh0*h0 = 0)
    __syncthreads();                 // slots visible

    #pragma unroll 1
    for (int t = 0; t < T; ++t) {
        // P1: XPART+CELL0 ; init+GATE whh1-ks0 (S0) ; commit D->S3,E->S4 ; load F,G
        COMMITQ(Ra, QS(3)); COMMITQ(Rb, QS(4));
        LOADQ(4, 1, Ra); LOADQ(3, 0, Rb);
        XPART; CELLW(0, c0);
        ACC_INIT(1); GATEP(1, 0, QS(0));
        BARX;
        // P2: GATE whh1-ks1 (S1) + wih1-ks0 (S2) ; commit F->S0 ; load H
        COMMITQ(Ra, QS(0)); LOADQ(3, 1, Ra);
        GATEP(1, 1, QS(1)); GATEP(0, 0, QS(2));
        BARX;
        // P3: GATE wih1-ks1 (S3) ; CELL1 ; init+GATE whh2-ks0 (S4) ; commit G->S1,H->S2 ; load I,J
        COMMITQ(Rb, QS(1)); COMMITQ(Ra, QS(2));
        LOADQ(0, 0, Rb); LOADQ(0, 1, Ra);
        GATEP(0, 1, QS(3));
        CELLW(1, c1);
        ACC_INIT(2); GATEP(2, 0, QS(4));
        BARX;
        // P4: GATE whh2-ks1 (S0) + wih2-ks0 (S1) ; commit I->S3,J->S4 ; load A',B'
        COMMITQ(Rb, QS(3)); COMMITQ(Ra, QS(4));
        LOADQ(2, 0, Rb); LOADQ(2, 1, Ra);
        GATEP(2, 1, QS(0)); GATEP(1, 0, QS(1));
        BARX;
        // P5: GATE wih2-ks1 (S2) ; CELL2 ; init+GATE whh0'-ks0 (S3) ; commit A'->S0 ; load C'
        COMMITQ(Rb, QS(0)); LOADQ(1, 0, Rb);
        GATEP(1, 1, QS(2));
        CELLW(2, c2);
        ACC_INIT(0); GATEP(0, 0, QS(3));
        BARX;
        // P6: GATE whh0'-ks1 (S4) ; MLP1 ; commit B'->S1 ; load D'
        COMMITQ(Ra, QS(1)); LOADQ(1, 1, Ra);
        GATEP(0, 1, QS(4));
        MLP1;
        BARX;
        // P7: MLP2 ; commit C'->S2 ; load E'
        COMMITQ(Rb, QS(2)); LOADQ(4, 0, Rb);
        MLP2M;
        BARX;
        // P8: MLP3 + out ring (+ flush every 2 steps)
        MLP3_OUT(t);
        if ((t & 1) == 1) {
            BARX;
            long tb = t - 1;
            if (tid < 768) {
                int e = tid / 6, rem = tid - e * 6;
                int st = rem / 3, j = rem - st * 3;
                out[(eg0 + e) * outs + (tb + st) * 3 + j] =
                    *(const float*)(lds + OUT_OFF + e * 24 + st * 12 + j * 4);
            }
        }
        BARX;                                       // step boundary (XFB visible)
    }

    // tail flush (T odd)
    if (T & 1) {
        if (tid < 384) {
            int e = tid & 127, j = tid >> 7;
            out[(eg0 + e) * outs + (long)(T - 1) * 3 + j] =
                *(const float*)(lds + OUT_OFF + e * 24 + ((T - 1) & 1) * 12 + j * 4);
        }
    }
}

extern "C" void kernel_launch(void* const* d_in, const int* in_sizes, int n_in,
                              void* d_out, int out_size, void* d_ws, size_t ws_size,
                              hipStream_t stream)
{
    const float* noise = (const float*)d_in[0];
    const float* wih0  = (const float*)d_in[1];
    const float* whh0  = (const float*)d_in[2];
    const float* bih0  = (const float*)d_in[3];
    const float* bhh0  = (const float*)d_in[4];
    const float* wih1  = (const float*)d_in[5];
    const float* whh1  = (const float*)d_in[6];
    const float* bih1  = (const float*)d_in[7];
    const float* bhh1  = (const float*)d_in[8];
    const float* wih2  = (const float*)d_in[9];
    const float* whh2  = (const float*)d_in[10];
    const float* bih2  = (const float*)d_in[11];
    const float* bhh2  = (const float*)d_in[12];
    const float* w1g   = (const float*)d_in[13];
    const float* b1g   = (const float*)d_in[14];
    const float* w2g   = (const float*)d_in[15];
    const float* b2g   = (const float*)d_in[16];
    const float* w3g   = (const float*)d_in[17];
    const float* b3g   = (const float*)d_in[18];
    const int*   lenp  = (const int*)d_in[19];
    float* out = (float*)d_out;

    int B = in_sizes[0] / 3;              // 32768
    int grid = B / BT;                    // 256 blocks = 1 per CU

    prep_weights<<<40, 256, 0, stream>>>(whh0, wih1, whh1, wih2, whh2);

    hipFuncSetAttribute((const void*)lstm_mfma,
                        hipFuncAttributeMaxDynamicSharedMemorySize, LDS_TOTAL);
    lstm_mfma<<<grid, NTHR, LDS_TOTAL, stream>>>(
        noise, wih0, whh0, bih0, bhh0, wih1, whh1, bih1, bhh1,
        wih2, whh2, bih2, bhh2, w1g, b1g, w2g, b2g, w3g, b3g, lenp, out);
}

// Round 19
// 3505.855 us; speedup vs baseline: 1.2064x; 1.0291x over previous
//
#include <hip/hip_runtime.h>

typedef __attribute__((ext_vector_type(4))) float  f32x4;
typedef __attribute__((ext_vector_type(8))) short  bf16x8;
typedef __attribute__((ext_vector_type(4))) short  bf16x4;

#define NTHR 1024
#define BT   128
#define L2E  1.4426950408889634f

// ---------------- LDS byte map (total 162512 <= 163840) ----------------
#define PLANE(L)   ((L)*16384)            // [128 elems][64 units] bf16, XOR-swizzled
#define QS(s)      (49152 + (s)*16384)    // 5-slot staging ring (80KB)
#define XFB_OFF    131072                 // [128][4] f32 feedback x (2048B)
#define Y1_OFF     133120                 // [128][36] bf16, 72B row (9216B)
#define Y2_OFF     142336                 // [128][18] bf16, 36B row (4608B)
#define BGL_OFF    146944                 // [3][256] f32 bias sums, log2e-scaled (3072B)
#define W0L_OFF    150016                 // [256][4] f32, 16B stride, log2e-scaled (4096B)
#define B3L_OFF    154112                 // [4] f32
#define W3L_OFF    154128                 // [3][16] f32 (192B)
#define W1L_OFF    154320                 // w1 frag blocks [4][64][16B] (4096B)
#define W2L_OFF    158416                 // [16][32] bf16 (1024B)
#define OUT_OFF    159440                 // [128][6] f32 out ring, 2 steps (3072B)
#define LDS_TOTAL  162512

// frag-ordered SINGLE-bf16 gate weights (log2e-prescaled): 5 mats * 32KB
__device__ __align__(16) unsigned char g_wsbuf[163840];

__device__ __forceinline__ unsigned short f2bf(float v) {
    unsigned int x = __float_as_uint(v);
    unsigned int r = x + 0x7fffu + ((x >> 16) & 1u);
    return (unsigned short)(r >> 16);
}
__device__ __forceinline__ float bf2f_lo(unsigned int d) { return __uint_as_float(d << 16); }
__device__ __forceinline__ float bf2f_hi(unsigned int d) { return __uint_as_float(d & 0xffff0000u); }

__device__ __forceinline__ float fsig2(float y) {   // sigmoid(x), y = x*log2e
    return __builtin_amdgcn_rcpf(1.0f + __builtin_amdgcn_exp2f(-y));
}
__device__ __forceinline__ float ftanh2(float y) {  // tanh(x), y = 2x*log2e
    return 1.0f - 2.0f * __builtin_amdgcn_rcpf(1.0f + __builtin_amdgcn_exp2f(y));
}
__device__ __forceinline__ float ftanhc(float c) {  // tanh(c)
    return 1.0f - 2.0f * __builtin_amdgcn_rcpf(1.0f + __builtin_amdgcn_exp2f(c * (2.0f * L2E)));
}

// ---------------- prologue: frag-order single-bf16 + log2e prescale ----------------
__global__ void prep_weights(const float* __restrict__ whh0, const float* __restrict__ wih1,
                             const float* __restrict__ whh1, const float* __restrict__ wih2,
                             const float* __restrict__ whh2)
{
    int gi = blockIdx.x * 256 + threadIdx.x;
    if (gi < 10240) {
        int m = gi / 2048;
        int rem = gi & 2047;
        int b = rem >> 6, l = rem & 63;
        int ks = b & 1, g = (b >> 1) & 3, ug = b >> 3;
        int row = g * 64 + ug * 16 + (l & 15);
        int kb  = ks * 32 + (l >> 4) * 8;
        float fac = (g == 2) ? (2.0f * L2E) : L2E;
        const float* src = (m == 0) ? whh0 : (m == 1) ? wih1 : (m == 2) ? whh1
                         : (m == 3) ? wih2 : whh2;
        unsigned short o[8];
        #pragma unroll
        for (int i = 0; i < 8; ++i)
            o[i] = f2bf(src[row * 64 + kb + i] * fac);
        unsigned char* dst = g_wsbuf + m * 32768 + b * 1024 + l * 16;
        #pragma unroll
        for (int i = 0; i < 8; ++i) ((unsigned short*)dst)[i] = o[i];
    }
}

#define MFMA_(A,B,C) __builtin_amdgcn_mfma_f32_16x16x32_bf16(A, B, C, 0, 0, 0)

// phase barrier (R8-proven, R18 A/B confirmed sched_barrier helps here)
#define BARX do { \
    asm volatile("s_waitcnt lgkmcnt(0)" ::: "memory"); \
    __builtin_amdgcn_s_barrier(); \
    __builtin_amdgcn_sched_barrier(0); \
    } while (0)

// staging: one dwordx4 per thread per 16KB quarter (m, ks)
#define LOADQ(m, ks, R) \
    R = *(const bf16x8*)(g_wsbuf + (m) * 32768 + \
        ((tid >> 6) * 2 + (ks)) * 1024 + (tid & 63) * 16)
#define COMMITQ(R, BUF) \
    *(bf16x8*)(lds + (BUF) + tid * 16) = R

#define ACC_INIT(L) do { \
    _Pragma("unroll") for (int g_ = 0; g_ < 4; ++g_) { \
        float b_ = *(const float*)(lds + BGL_OFF + ((L) * 256 + g_ * 64 + u) * 4); \
        f32x4 t_ = {b_, b_, b_, b_}; \
        acc[g_][0] = t_; acc[g_][1] = t_; \
    } } while (0)

// gate pass: acc += bf16(h_plane) x staged quarter (6 ds_read_b128, 16 MFMA)
#define GATEP(APL, ks, BUF) do { \
    bf16x8 b_[4]; \
    _Pragma("unroll") for (int g_ = 0; g_ < 4; ++g_) \
        b_[g_] = *(const bf16x8*)(lds + (BUF) + (ug * 4 + g_) * 1024 + lane * 16); \
    _Pragma("unroll") for (int mt_ = 0; mt_ < 2; ++mt_) { \
        int ab_ = (((mbase + mt_ * 16 + l15) * 128 + (ks) * 64 + l4 * 16)) ^ rswz; \
        bf16x8 ah_ = *(const bf16x8*)(lds + PLANE(APL) + ab_); \
        _Pragma("unroll") for (int g_ = 0; g_ < 4; ++g_) \
            acc[g_][mt_] = MFMA_(ah_, b_[g_], acc[g_][mt_]); \
    } } while (0)

#define CELLW(L, CARR) do { \
    _Pragma("unroll") for (int mt_ = 0; mt_ < 2; ++mt_) \
    _Pragma("unroll") for (int r_ = 0; r_ < 4; ++r_) { \
        float gi_ = fsig2(acc[0][mt_][r_]); \
        float gf_ = fsig2(acc[1][mt_][r_]); \
        float gg_ = ftanh2(acc[2][mt_][r_]); \
        float go_ = fsig2(acc[3][mt_][r_]); \
        float cn_ = gf_ * CARR[mt_ * 4 + r_] + gi_ * gg_; \
        CARR[mt_ * 4 + r_] = cn_; \
        float hn_ = go_ * ftanhc(cn_); \
        int e_ = mbase + mt_ * 16 + l4 * 4 + r_; \
        int wb_ = ((e_ * 128 + u * 2)) ^ ((e_ & 7) << 4); \
        *(unsigned short*)(lds + PLANE(L) + wb_) = f2bf(hn_); \
    } } while (0)

#define XPART do { \
    _Pragma("unroll") for (int mt_ = 0; mt_ < 2; ++mt_) \
    _Pragma("unroll") for (int r_ = 0; r_ < 4; ++r_) { \
        int e_ = mbase + mt_ * 16 + l4 * 4 + r_; \
        f32x4 xv_ = *(const f32x4*)(lds + XFB_OFF + e_ * 16); \
        _Pragma("unroll") for (int g_ = 0; g_ < 4; ++g_) { \
            f32x4 w0_ = *(const f32x4*)(lds + W0L_OFF + (g_ * 64 + u) * 16); \
            acc[g_][mt_][r_] += xv_.x * w0_.x + xv_.y * w0_.y + xv_.z * w0_.z; \
        } } } while (0)

// y1 via MFMA, w1 frags from resident LDS (2 MFMA)
#define MLP1 do { \
    int Mt_ = wv >> 1; \
    f32x4 a1_ = {b1r, b1r, b1r, b1r}; \
    bf16x8 wh0_ = *(const bf16x8*)(lds + W1L_OFF + (hf * 2 + 0) * 1024 + lane * 16); \
    bf16x8 wh1_ = *(const bf16x8*)(lds + W1L_OFF + (hf * 2 + 1) * 1024 + lane * 16); \
    { int ab_ = (((Mt_ * 16 + l15) * 128 + 0 * 64 + l4 * 16)) ^ rswz; \
      bf16x8 ah_ = *(const bf16x8*)(lds + PLANE(2) + ab_); \
      a1_ = MFMA_(ah_, wh0_, a1_); } \
    { int ab_ = (((Mt_ * 16 + l15) * 128 + 1 * 64 + l4 * 16)) ^ rswz; \
      bf16x8 ah_ = *(const bf16x8*)(lds + PLANE(2) + ab_); \
      a1_ = MFMA_(ah_, wh1_, a1_); } \
    _Pragma("unroll") for (int r_ = 0; r_ < 4; ++r_) { \
        float y_ = a1_[r_]; y_ = (y_ >= 0.f) ? y_ : 0.01f * y_; \
        int e_ = Mt_ * 16 + l4 * 4 + r_; \
        *(unsigned short*)(lds + Y1_OFF + e_ * 72 + hf * 32 + l15 * 2) = f2bf(y_); \
    } } while (0)

// y2 via MFMA on waves 0..7 (1 MFMA)
#define MLP2M do { \
    if (wv < 8) { \
        bf16x4 alo_ = *(const bf16x4*)(lds + Y1_OFF + (wv * 16 + l15) * 72 + l4 * 16); \
        bf16x4 ahi_ = *(const bf16x4*)(lds + Y1_OFF + (wv * 16 + l15) * 72 + l4 * 16 + 8); \
        bf16x8 af_ = {alo_[0], alo_[1], alo_[2], alo_[3], \
                      ahi_[0], ahi_[1], ahi_[2], ahi_[3]}; \
        bf16x8 w2f_ = *(const bf16x8*)(lds + W2L_OFF + (l15 * 32 + l4 * 8) * 2); \
        f32x4 a2_ = {b2r, b2r, b2r, b2r}; \
        a2_ = MFMA_(af_, w2f_, a2_); \
        _Pragma("unroll") for (int r_ = 0; r_ < 4; ++r_) { \
            float y_ = a2_[r_]; y_ = (y_ >= 0.f) ? y_ : 0.01f * y_; \
            int e_ = wv * 16 + l4 * 4 + r_; \
            *(unsigned short*)(lds + Y2_OFF + e_ * 36 + l15 * 2) = f2bf(y_); \
        } } } while (0)

#define MLP3_OUT(tc) do { \
    if (tid < 384) { \
        int e3_ = tid & 127, r3_ = tid >> 7; \
        float a3_ = *(const float*)(lds + B3L_OFF + r3_ * 4); \
        _Pragma("unroll") for (int kd_ = 0; kd_ < 8; ++kd_) { \
            unsigned int d_ = *(const unsigned int*)(lds + Y2_OFF + e3_ * 36 + kd_ * 4); \
            a3_ = fmaf(bf2f_lo(d_), *(const float*)(lds + W3L_OFF + (r3_ * 16 + kd_ * 2) * 4),     a3_); \
            a3_ = fmaf(bf2f_hi(d_), *(const float*)(lds + W3L_OFF + (r3_ * 16 + kd_ * 2 + 1) * 4), a3_); \
        } \
        float y_ = (a3_ >= 0.f) ? a3_ : 0.01f * a3_; \
        *(float*)(lds + XFB_OFF + e3_ * 16 + r3_ * 4) = y_; \
        *(float*)(lds + OUT_OFF + e3_ * 24 + ((tc) & 1) * 12 + r3_ * 4) = y_; \
    } } while (0)

// ---------------- main persistent kernel ----------------
// quarters: I/J = whh0 (0,0/1); C/D = wih1 (1,0/1); A/B = whh1 (2,0/1);
//           G/H = wih2 (3,0/1); E/F = whh2 (4,0/1)
extern "C" __global__ void __launch_bounds__(NTHR)
__attribute__((amdgpu_waves_per_eu(4, 4)))
lstm_mfma(const float* __restrict__ noise,
          const float* __restrict__ wih0, const float* __restrict__ whh0,
          const float* __restrict__ bih0, const float* __restrict__ bhh0,
          const float* __restrict__ wih1, const float* __restrict__ whh1,
          const float* __restrict__ bih1, const float* __restrict__ bhh1,
          const float* __restrict__ wih2, const float* __restrict__ whh2,
          const float* __restrict__ bih2, const float* __restrict__ bhh2,
          const float* __restrict__ w1g, const float* __restrict__ b1g,
          const float* __restrict__ w2g, const float* __restrict__ b2g,
          const float* __restrict__ w3g, const float* __restrict__ b3g,
          const int* __restrict__ lenp, float* __restrict__ out)
{
    extern __shared__ unsigned char lds[];
    const int tid  = threadIdx.x;
    const int lane = tid & 63;
    const int wv   = tid >> 6;       // wave 0..15
    const int ug   = wv & 3;         // unit group (16 units)
    const int mh   = wv >> 2;        // M quarter 0..3
    const int l15  = lane & 15;
    const int l4   = lane >> 4;      // k-group
    const int u    = ug * 16 + l15;  // unit 0..63
    const int mbase = mh * 32;
    const int rswz  = (lane & 7) << 4;
    const int hf    = wv & 1;        // MLP1 col-half
    const int T = *lenp;
    const long eg0  = (long)blockIdx.x * BT;
    const long outs = 3L * T;

    // per-thread recurrent c state
    float c0[8], c1[8], c2[8];
    #pragma unroll
    for (int i = 0; i < 8; ++i) { c0[i] = 0.f; c1[i] = 0.f; c2[i] = 0.f; }

    const float b1r = b1g[hf * 16 + l15];
    const float b2r = b2g[l15];

    // staging regs
    bf16x8 Ra, Rb;

    // prologue loads: A=(2,0), B=(2,1)
    LOADQ(2, 0, Ra);
    LOADQ(2, 1, Rb);

    // ---- LDS init ----
    for (int i = tid; i < 49152 / 4; i += NTHR) ((unsigned int*)lds)[i] = 0u;  // h planes = 0
    if (tid < BT) {
        const float* np = noise + (eg0 + tid) * 3;
        f32x4 xv = {np[0], np[1], np[2], 0.f};
        *(f32x4*)(lds + XFB_OFF + tid * 16) = xv;
    }
    if (tid < 768) {                                   // bias sums, log2e-scaled
        int l = tid >> 8, r = tid & 255, g = r >> 6;
        float fac = (g == 2) ? (2.0f * L2E) : L2E;
        const float* bi = (l == 0) ? bih0 : ((l == 1) ? bih1 : bih2);
        const float* bh = (l == 0) ? bhh0 : ((l == 1) ? bhh1 : bhh2);
        *(float*)(lds + BGL_OFF + tid * 4) = (bi[r] + bh[r]) * fac;
    }
    if (tid < 256) {                                   // wih0, log2e-scaled
        int g = tid >> 6;
        float fac = (g == 2) ? (2.0f * L2E) : L2E;
        f32x4 wv0 = {wih0[tid * 3] * fac, wih0[tid * 3 + 1] * fac,
                     wih0[tid * 3 + 2] * fac, 0.f};
        *(f32x4*)(lds + W0L_OFF + tid * 16) = wv0;
    }
    if (tid < 256) {                                   // w1 frag blocks
        int b = tid >> 6, l = tid & 63;
        int hh = b >> 1, ks = b & 1;
        int row = hh * 16 + (l & 15);
        int kb  = ks * 32 + (l >> 4) * 8;
        unsigned short o[8];
        #pragma unroll
        for (int i = 0; i < 8; ++i) o[i] = f2bf(w1g[row * 64 + kb + i]);
        #pragma unroll
        for (int i = 0; i < 8; ++i)
            *(unsigned short*)(lds + W1L_OFF + b * 1024 + l * 16 + i * 2) = o[i];
    }
    if (tid < 512) *(unsigned short*)(lds + W2L_OFF + tid * 2) = f2bf(w2g[tid]);
    if (tid < 3)   *(float*)(lds + B3L_OFF + tid * 4) = b3g[tid];
    if (tid < 48)  *(float*)(lds + W3L_OFF + tid * 4) = w3g[tid];

    __syncthreads();                 // init visible
    COMMITQ(Ra, QS(0));              // A -> S0
    COMMITQ(Rb, QS(1));              // B -> S1
    LOADQ(1, 0, Ra);                 // C
    COMMITQ(Ra, QS(2));              // C -> S2
    LOADQ(1, 1, Ra);                 // D -> Ra
    LOADQ(4, 0, Rb);                 // E -> Rb

    f32x4 acc[4][2];
    ACC_INIT(0);                     // t=0 layer0 gates = bias (whh0*h0 = 0)
    __syncthreads();                 // slots visible

    #pragma unroll 1
    for (int t = 0; t < T; ++t) {
        // P1: XPART+CELL0 ; init+GATE whh1-ks0 (S0) ; commit D->S3,E->S4 ; load F,G
        COMMITQ(Ra, QS(3)); COMMITQ(Rb, QS(4));
        LOADQ(4, 1, Ra); LOADQ(3, 0, Rb);
        XPART; CELLW(0, c0);
        ACC_INIT(1); GATEP(1, 0, QS(0));
        BARX;
        // P2: GATE whh1-ks1 (S1) + wih1-ks0 (S2) ; commit F->S0 ; load H
        COMMITQ(Ra, QS(0)); LOADQ(3, 1, Ra);
        GATEP(1, 1, QS(1)); GATEP(0, 0, QS(2));
        BARX;
        // P3: GATE wih1-ks1 (S3) ; CELL1 ; init+GATE whh2-ks0 (S4) ; commit G->S1,H->S2 ; load I,J
        COMMITQ(Rb, QS(1)); COMMITQ(Ra, QS(2));
        LOADQ(0, 0, Rb); LOADQ(0, 1, Ra);
        GATEP(0, 1, QS(3));
        CELLW(1, c1);
        ACC_INIT(2); GATEP(2, 0, QS(4));
        BARX;
        // P4: GATE whh2-ks1 (S0) + wih2-ks0 (S1) ; commit I->S3,J->S4 ; load A',B'
        COMMITQ(Rb, QS(3)); COMMITQ(Ra, QS(4));
        LOADQ(2, 0, Rb); LOADQ(2, 1, Ra);
        GATEP(2, 1, QS(0)); GATEP(1, 0, QS(1));
        BARX;
        // P5: GATE wih2-ks1 (S2) ; CELL2 ; init+GATE whh0'-ks0 (S3) ; commit A'->S0 ; load C'
        COMMITQ(Rb, QS(0)); LOADQ(1, 0, Rb);
        GATEP(1, 1, QS(2));
        CELLW(2, c2);
        ACC_INIT(0); GATEP(0, 0, QS(3));
        BARX;
        // P6: GATE whh0'-ks1 (S4) ; MLP1 ; commit B'->S1 ; load D'
        COMMITQ(Ra, QS(1)); LOADQ(1, 1, Ra);
        GATEP(0, 1, QS(4));
        MLP1;
        BARX;
        // P7: MLP2 ; commit C'->S2 ; load E'
        COMMITQ(Rb, QS(2)); LOADQ(4, 0, Rb);
        MLP2M;
        BARX;
        // P8: MLP3 + out ring (+ flush every 2 steps)
        MLP3_OUT(t);
        if ((t & 1) == 1) {
            BARX;
            long tb = t - 1;
            if (tid < 768) {
                int e = tid / 6, rem = tid - e * 6;
                int st = rem / 3, j = rem - st * 3;
                out[(eg0 + e) * outs + (tb + st) * 3 + j] =
                    *(const float*)(lds + OUT_OFF + e * 24 + st * 12 + j * 4);
            }
        }
        BARX;                                       // step boundary (XFB visible)
    }

    // tail flush (T odd)
    if (T & 1) {
        if (tid < 384) {
            int e = tid & 127, j = tid >> 7;
            out[(eg0 + e) * outs + (long)(T - 1) * 3 + j] =
                *(const float*)(lds + OUT_OFF + e * 24 + ((T - 1) & 1) * 12 + j * 4);
        }
    }
}

extern "C" void kernel_launch(void* const* d_in, const int* in_sizes, int n_in,
                              void* d_out, int out_size, void* d_ws, size_t ws_size,
                              hipStream_t stream)
{
    const float* noise = (const float*)d_in[0];
    const float* wih0  = (const float*)d_in[1];
    const float* whh0  = (const float*)d_in[2];
    const float* bih0  = (const float*)d_in[3];
    const float* bhh0  = (const float*)d_in[4];
    const float* wih1  = (const float*)d_in[5];
    const float* whh1  = (const float*)d_in[6];
    const float* bih1  = (const float*)d_in[7];
    const float* bhh1  = (const float*)d_in[8];
    const float* wih2  = (const float*)d_in[9];
    const float* whh2  = (const float*)d_in[10];
    const float* bih2  = (const float*)d_in[11];
    const float* bhh2  = (const float*)d_in[12];
    const float* w1g   = (const float*)d_in[13];
    const float* b1g   = (const float*)d_in[14];
    const float* w2g   = (const float*)d_in[15];
    const float* b2g   = (const float*)d_in[16];
    const float* w3g   = (const float*)d_in[17];
    const float* b3g   = (const float*)d_in[18];
    const int*   lenp  = (const int*)d_in[19];
    float* out = (float*)d_out;

    int B = in_sizes[0] / 3;              // 32768
    int grid = B / BT;                    // 256 blocks = 1 per CU

    prep_weights<<<40, 256, 0, stream>>>(whh0, wih1, whh1, wih2, whh2);

    hipFuncSetAttribute((const void*)lstm_mfma,
                        hipFuncAttributeMaxDynamicSharedMemorySize, LDS_TOTAL);
    lstm_mfma<<<grid, NTHR, LDS_TOTAL, stream>>>(
        noise, wih0, whh0, bih0, bhh0, wih1, whh1, bih1, bhh1,
        wih2, whh2, bih2, bhh2, w1g, b1g, w2g, b2g, w3g, b3g, lenp, out);
}